// Round 7
// baseline (42.774 us; speedup 1.0000x reference)
//
#include <hip/hip_runtime.h>

typedef _Float16 half4 __attribute__((ext_vector_type(4)));
typedef _Float16 h2 __attribute__((ext_vector_type(2)));
typedef float f32x4 __attribute__((ext_vector_type(4)));

#define SINCONST 0.07957747154594767f  // 0.5 rad in revolutions

__device__ __forceinline__ unsigned int pk(float a, float b) {
    return __builtin_bit_cast(unsigned int, __builtin_amdgcn_cvt_pkrtz(a, b));
}

// state factors for one patch: a = (c0c1,c0s1,s0c1,s0s1) dup-packed, q = (c2c3,c2s3,s2c3,s2s3)
__device__ __forceinline__ void factors(float px0, float px1, float px2, float px3,
                                        uint4& ad, uint2& qd) {
    float t0 = px0 * SINCONST, t1 = px1 * SINCONST;
    float t2 = px2 * SINCONST, t3 = px3 * SINCONST;
    float s0 = __builtin_amdgcn_sinf(t0), c0 = __builtin_amdgcn_cosf(t0);
    float s1 = __builtin_amdgcn_sinf(t1), c1 = __builtin_amdgcn_cosf(t1);
    float s2 = __builtin_amdgcn_sinf(t2), c2 = __builtin_amdgcn_cosf(t2);
    float s3 = __builtin_amdgcn_sinf(t3), c3 = __builtin_amdgcn_cosf(t3);
    float a0 = c0 * c1, a1 = c0 * s1, a2 = s0 * c1, a3 = s0 * s1;
    float q0 = c2 * c3, q1 = c2 * s3, q2 = s2 * c3, q3 = s2 * s3;
    ad.x = pk(a0, a0); ad.y = pk(a1, a1); ad.z = pk(a2, a2); ad.w = pk(a3, a3);
    qd.x = pk(q0, q1); qd.y = pk(q2, q3);
}

// Per wave macro-iter: 128 patches (64 aligned pairs; one float4 top + one float4 bottom per lane).
// LDS per wave (768 dwords, SINGLE buffer -- wave-private, same-wave DS ops are in-order):
//   adup[128][4] u32 @ [0,512), qv[128] u32x2 @ [512,768).
// Phase2: 8 MFMA sub-batches of 16 patches; fragment conventions identical to validated kernel.
__global__ __launch_bounds__(256) void quanv(
    const float* __restrict__ x,
    const float* __restrict__ U,
    float* __restrict__ out,
    int total, int ipw, int rem)
{
    __shared__ __align__(16) unsigned int smem[4 * 768];  // 12 KiB -> 8 blocks/CU

    const int tid  = threadIdx.x;
    const int lane = tid & 63;
    const int wib  = tid >> 6;
    const int wave = (blockIdx.x * 256 + tid) >> 6;
    const int p16  = lane & 15;
    const int g    = lane >> 4;

    unsigned int* buf = smem + wib * 768;

    // A1 = U fragment: U[p16][4g+i]  (validated layout)
    half4 aU;
    {
        const float* up = U + p16 * 16 + 4 * g;
        aU[0] = (_Float16)up[0];
        aU[1] = (_Float16)up[1];
        aU[2] = (_Float16)up[2];
        aU[3] = (_Float16)up[3];
    }
    // A2 = tiled PauliZ signs: Ztile[p16][e=4g+i], wire=p16&3 (exact in f16)
    half4 aS;
    {
        int w = p16 & 3;
        #pragma unroll
        for (int i = 0; i < 4; ++i) {
            int e = 4 * g + i;
            aS[i] = ((e >> (3 - w)) & 1) ? (_Float16)-1.f : (_Float16)1.f;
        }
    }

    int cnt = ipw + (wave < rem ? 1 : 0);
    if (cnt <= 0) return;
    const int mac0 = wave * ipw + (wave < rem ? wave : rem);
    const int nPairs = total >> 1;

    // load pixels for this lane's patch pair of macro-iter j (index-clamped, branch-free)
    auto ldp = [&](int j, float4& t4, float4& b4) {
        int PR = (mac0 + j) * 64 + lane;
        if (PR >= nPairs) PR = nPairs - 1;
        int P   = PR * 2;
        int img = P / 196;                  // compiler magic-mul
        int pp  = P - img * 196;            // even, [0,194]
        int r   = (pp * 2341) >> 15;        // pp/14
        const float4* ptr = reinterpret_cast<const float4*>(x + img * 784 + 2 * pp + 28 * r);
        t4 = ptr[0];                        // top row: patches P,P+1
        b4 = ptr[7];                        // +28 floats
    };

    float4 cT, cB, nT, nB;
    ldp(0, cT, cB);
    ldp(1, nT, nB);

    for (int j = 0; j < cnt; ++j) {
        // prefetch j+2 (depth-2 pipeline, clamped so no branch needed)
        float4 fT, fB;
        ldp(j + 2, fT, fB);

        // ---- phase 1: two patches -> f16 factors -> LDS ----
        uint4 adA, adB; uint2 qdA, qdB;
        factors(cT.x, cT.y, cB.x, cB.y, adA, qdA);   // patch P   (even)
        factors(cT.z, cT.w, cB.z, cB.w, adB, qdB);   // patch P+1

        *reinterpret_cast<uint4*>(buf + 8 * lane)     = adA;   // adup rows 2l, 2l+1
        *reinterpret_cast<uint4*>(buf + 8 * lane + 4) = adB;
        uint4 qq = make_uint4(qdA.x, qdA.y, qdB.x, qdB.y);     // qv rows 2l, 2l+1
        *reinterpret_cast<uint4*>(buf + 512 + 4 * lane) = qq;

        // ---- phase 2: 8 MFMA sub-batches ----
        const int pbase = (mac0 + j) * 128;
        #pragma unroll
        for (int t = 0; t < 8; ++t) {
            const int pt = t * 16 + p16;
            unsigned int adw = buf[pt * 4 + g];                              // imm 256*t
            uint2 qw = *reinterpret_cast<const uint2*>(buf + 512 + 2 * pt);  // imm 2048+128*t

            h2 ag  = __builtin_bit_cast(h2, adw);
            h2 q01 = __builtin_bit_cast(h2, qw.x);
            h2 q23 = __builtin_bit_cast(h2, qw.y);
            h2 blo = ag * q01;                     // v_pk_mul_f16
            h2 bhi = ag * q23;
            half4 bST = __builtin_shufflevector(blo, bhi, 0, 1, 2, 3);

            const f32x4 zero4 = {0.f, 0.f, 0.f, 0.f};
            f32x4 y = __builtin_amdgcn_mfma_f32_16x16x16f16(aU, bST, zero4, 0, 0, 0);

            h2 y01 = __builtin_bit_cast(h2, pk(y[0], y[1]));
            h2 y23 = __builtin_bit_cast(h2, pk(y[2], y[3]));
            h2 p01 = y01 * y01;
            h2 p23 = y23 * y23;
            half4 bP = __builtin_shufflevector(p01, p23, 0, 1, 2, 3);

            f32x4 m = __builtin_amdgcn_mfma_f32_16x16x16f16(aS, bP, zero4, 0, 0, 0);

            int Ps = pbase + pt;
            if (g == 0 && Ps < total) {
                float4 res = make_float4(m[0], m[1], m[2], m[3]);
                *reinterpret_cast<float4*>(out + (size_t)Ps * 4) = res;
            }
        }

        cT = nT; cB = nB;
        nT = fT; nB = fB;
    }
}

extern "C" void kernel_launch(void* const* d_in, const int* in_sizes, int n_in,
                              void* d_out, int out_size, void* d_ws, size_t ws_size,
                              hipStream_t stream) {
    const float* x = (const float*)d_in[0];
    const float* U = (const float*)d_in[1];
    float* out = (float*)d_out;

    int B = in_sizes[0] / 784;
    int total = B * 196;                  // 6,422,528 patches
    int nPairs = total / 2;               // 3,211,264 aligned pairs
    int nmac = (nPairs + 63) / 64;        // 50,176 macro-iters (128 patches each)

    int nblocks = 2048;                   // 8/CU, all co-resident at 12 KiB LDS
    int nwaves = nblocks * (256 / 64);    // 8192 waves -> 6-7 macro-iters/wave
    int ipw = nmac / nwaves;
    int rem = nmac % nwaves;

    quanv<<<nblocks, 256, 0, stream>>>(x, U, out, total, ipw, rem);
}

// Round 9
// 41.698 us; speedup vs baseline: 1.0258x; 1.0258x over previous
//
#include <hip/hip_runtime.h>

typedef _Float16 half4 __attribute__((ext_vector_type(4)));
typedef _Float16 h2 __attribute__((ext_vector_type(2)));
typedef float f32x4 __attribute__((ext_vector_type(4)));

#define SINCONST 0.07957747154594767f  // 0.5 rad in revolutions

__device__ __forceinline__ unsigned int pk(float a, float b) {
    return __builtin_bit_cast(unsigned int, __builtin_amdgcn_cvt_pkrtz(a, b));
}

// state factors for one patch: a = (c0c1,c0s1,s0c1,s0s1) dup-packed, q = (c2c3,c2s3,s2c3,s2s3)
__device__ __forceinline__ void factors(float px0, float px1, float px2, float px3,
                                        uint4& ad, uint2& qd) {
    float t0 = px0 * SINCONST, t1 = px1 * SINCONST;
    float t2 = px2 * SINCONST, t3 = px3 * SINCONST;
    float s0 = __builtin_amdgcn_sinf(t0), c0 = __builtin_amdgcn_cosf(t0);
    float s1 = __builtin_amdgcn_sinf(t1), c1 = __builtin_amdgcn_cosf(t1);
    float s2 = __builtin_amdgcn_sinf(t2), c2 = __builtin_amdgcn_cosf(t2);
    float s3 = __builtin_amdgcn_sinf(t3), c3 = __builtin_amdgcn_cosf(t3);
    float a0 = c0 * c1, a1 = c0 * s1, a2 = s0 * c1, a3 = s0 * s1;
    float q0 = c2 * c3, q1 = c2 * s3, q2 = s2 * c3, q3 = s2 * s3;
    ad.x = pk(a0, a0); ad.y = pk(a1, a1); ad.z = pk(a2, a2); ad.w = pk(a3, a3);
    qd.x = pk(q0, q1); qd.y = pk(q2, q3);
}

// Per wave macro-iter: 128 patches (64 aligned pairs; one float4 top + one float4 bottom per lane).
// LDS per wave (768 dwords, single buffer -- wave-private, same-wave DS ops in-order):
//   adup[128][4] u32 @ [0,512), qv[128] u32x2 @ [512,768).
// Phase2: 8 MFMA sub-batches of 16 patches; fragment conventions identical to validated kernel.
// Out stores are NON-TEMPORAL: out is write-once, keep L3 for x.
__global__ __launch_bounds__(256) void quanv(
    const float* __restrict__ x,
    const float* __restrict__ U,
    float* __restrict__ out,
    int total, int ipw, int rem)
{
    __shared__ __align__(16) unsigned int smem[4 * 768];  // 12 KiB -> 8 blocks/CU

    const int tid  = threadIdx.x;
    const int lane = tid & 63;
    const int wib  = tid >> 6;
    const int wave = (blockIdx.x * 256 + tid) >> 6;
    const int p16  = lane & 15;
    const int g    = lane >> 4;

    unsigned int* buf = smem + wib * 768;

    // A1 = U fragment: U[p16][4g+i]  (validated layout)
    half4 aU;
    {
        const float* up = U + p16 * 16 + 4 * g;
        aU[0] = (_Float16)up[0];
        aU[1] = (_Float16)up[1];
        aU[2] = (_Float16)up[2];
        aU[3] = (_Float16)up[3];
    }
    // A2 = tiled PauliZ signs: Ztile[p16][e=4g+i], wire=p16&3 (exact in f16)
    half4 aS;
    {
        int w = p16 & 3;
        #pragma unroll
        for (int i = 0; i < 4; ++i) {
            int e = 4 * g + i;
            aS[i] = ((e >> (3 - w)) & 1) ? (_Float16)-1.f : (_Float16)1.f;
        }
    }

    int cnt = ipw + (wave < rem ? 1 : 0);
    if (cnt <= 0) return;
    const int mac0 = wave * ipw + (wave < rem ? wave : rem);
    const int nPairs = total >> 1;

    // load pixels for this lane's patch pair of macro-iter j (index-clamped, branch-free)
    auto ldp = [&](int j, float4& t4, float4& b4) {
        int PR = (mac0 + j) * 64 + lane;
        if (PR >= nPairs) PR = nPairs - 1;
        int P   = PR * 2;
        int img = P / 196;                  // compiler magic-mul
        int pp  = P - img * 196;            // even, [0,194]
        int r   = (pp * 2341) >> 15;        // pp/14
        const float4* ptr = reinterpret_cast<const float4*>(x + img * 784 + 2 * pp + 28 * r);
        t4 = ptr[0];                        // top row: patches P,P+1
        b4 = ptr[7];                        // +28 floats
    };

    float4 cT, cB, nT, nB;
    ldp(0, cT, cB);
    ldp(1, nT, nB);

    for (int j = 0; j < cnt; ++j) {
        // prefetch j+2 (depth-2 pipeline, clamped so no branch needed)
        float4 fT, fB;
        ldp(j + 2, fT, fB);

        // ---- phase 1: two patches -> f16 factors -> LDS ----
        uint4 adA, adB; uint2 qdA, qdB;
        factors(cT.x, cT.y, cB.x, cB.y, adA, qdA);   // patch P   (even)
        factors(cT.z, cT.w, cB.z, cB.w, adB, qdB);   // patch P+1

        *reinterpret_cast<uint4*>(buf + 8 * lane)     = adA;   // adup rows 2l, 2l+1
        *reinterpret_cast<uint4*>(buf + 8 * lane + 4) = adB;
        uint4 qq = make_uint4(qdA.x, qdA.y, qdB.x, qdB.y);     // qv rows 2l, 2l+1
        *reinterpret_cast<uint4*>(buf + 512 + 4 * lane) = qq;

        // ---- phase 2: 8 MFMA sub-batches ----
        const int pbase = (mac0 + j) * 128;
        #pragma unroll
        for (int t = 0; t < 8; ++t) {
            const int pt = t * 16 + p16;
            unsigned int adw = buf[pt * 4 + g];                              // imm 256*t
            uint2 qw = *reinterpret_cast<const uint2*>(buf + 512 + 2 * pt);  // imm 2048+128*t

            h2 ag  = __builtin_bit_cast(h2, adw);
            h2 q01 = __builtin_bit_cast(h2, qw.x);
            h2 q23 = __builtin_bit_cast(h2, qw.y);
            h2 blo = ag * q01;                     // v_pk_mul_f16
            h2 bhi = ag * q23;
            half4 bST = __builtin_shufflevector(blo, bhi, 0, 1, 2, 3);

            const f32x4 zero4 = {0.f, 0.f, 0.f, 0.f};
            f32x4 y = __builtin_amdgcn_mfma_f32_16x16x16f16(aU, bST, zero4, 0, 0, 0);

            h2 y01 = __builtin_bit_cast(h2, pk(y[0], y[1]));
            h2 y23 = __builtin_bit_cast(h2, pk(y[2], y[3]));
            h2 p01 = y01 * y01;
            h2 p23 = y23 * y23;
            half4 bP = __builtin_shufflevector(p01, p23, 0, 1, 2, 3);

            f32x4 m = __builtin_amdgcn_mfma_f32_16x16x16f16(aS, bP, zero4, 0, 0, 0);

            int Ps = pbase + pt;
            if (g == 0 && Ps < total) {
                // non-temporal: out is write-once, don't evict x from L2/L3
                __builtin_nontemporal_store(m, reinterpret_cast<f32x4*>(out + (size_t)Ps * 4));
            }
        }

        cT = nT; cB = nB;
        nT = fT; nB = fB;
    }
}

extern "C" void kernel_launch(void* const* d_in, const int* in_sizes, int n_in,
                              void* d_out, int out_size, void* d_ws, size_t ws_size,
                              hipStream_t stream) {
    const float* x = (const float*)d_in[0];
    const float* U = (const float*)d_in[1];
    float* out = (float*)d_out;

    int B = in_sizes[0] / 784;
    int total = B * 196;                  // 6,422,528 patches
    int nPairs = total / 2;               // 3,211,264 aligned pairs
    int nmac = (nPairs + 63) / 64;        // 50,176 macro-iters (128 patches each)

    // 1792 blocks = 7 blocks/CU (12 KiB LDS each), 7168 waves:
    // 50176 / 7168 = 7 exactly -> rem 0, perfectly balanced, no tail.
    int nblocks = 1792;
    int nwaves = nblocks * (256 / 64);
    int ipw = nmac / nwaves;
    int rem = nmac % nwaves;

    quanv<<<nblocks, 256, 0, stream>>>(x, U, out, total, ipw, rem);
}

// Round 10
// 41.000 us; speedup vs baseline: 1.0433x; 1.0170x over previous
//
#include <hip/hip_runtime.h>

typedef _Float16 half4 __attribute__((ext_vector_type(4)));
typedef _Float16 h2 __attribute__((ext_vector_type(2)));
typedef float f32x4 __attribute__((ext_vector_type(4)));

#define SINCONST 0.07957747154594767f  // 0.5 rad in revolutions

__device__ __forceinline__ unsigned int pk(float a, float b) {
    return __builtin_bit_cast(unsigned int, __builtin_amdgcn_cvt_pkrtz(a, b));
}

// factors for one patch: a = (c0c1,c0s1,s0c1,s0s1) -> 2 dwords, q = (c2c3,c2s3,s2c3,s2s3) -> 2 dwords
__device__ __forceinline__ void factors(float px0, float px1, float px2, float px3,
                                        uint2& aw, uint2& qw) {
    float t0 = px0 * SINCONST, t1 = px1 * SINCONST;
    float t2 = px2 * SINCONST, t3 = px3 * SINCONST;
    float s0 = __builtin_amdgcn_sinf(t0), c0 = __builtin_amdgcn_cosf(t0);
    float s1 = __builtin_amdgcn_sinf(t1), c1 = __builtin_amdgcn_cosf(t1);
    float s2 = __builtin_amdgcn_sinf(t2), c2 = __builtin_amdgcn_cosf(t2);
    float s3 = __builtin_amdgcn_sinf(t3), c3 = __builtin_amdgcn_cosf(t3);
    float a0 = c0 * c1, a1 = c0 * s1, a2 = s0 * c1, a3 = s0 * s1;
    float q0 = c2 * c3, q1 = c2 * s3, q2 = s2 * c3, q3 = s2 * s3;
    aw.x = pk(a0, a1); aw.y = pk(a2, a3);
    qw.x = pk(q0, q1); qw.y = pk(q2, q3);
}

// Software-pipelined: factors for iter j+1 -> LDS buf (j+1)&1 OVERLAP phase2 on buf j&1.
// LDS per wave: 2 buffers x (a[128] f16x4 @ [0,256) dw + q[128] u32x2 @ [256,512) dw) = 4 KiB.
// Phase2: 8 MFMA sub-batches; every lane-group holds identical results (Ztile rows repeat
// mod 4), so group g stores sub-batch g -> two full-wave 1 KiB coalesced nt-stores per iter.
__global__ __launch_bounds__(256, 7) void quanv(
    const float* __restrict__ x,
    const float* __restrict__ U,
    float* __restrict__ out,
    int total, int ipw, int rem)
{
    __shared__ __align__(16) unsigned int smem[4 * 1024];  // 16 KiB -> 7 blocks/CU

    const int tid  = threadIdx.x;
    const int lane = tid & 63;
    const int wib  = tid >> 6;
    const int wave = (blockIdx.x * 256 + tid) >> 6;
    const int p16  = lane & 15;
    const int g    = lane >> 4;

    unsigned int* wbase = smem + wib * 1024;

    // A1 = U fragment: U[p16][4g+i]  (validated layout)
    half4 aU;
    {
        const float* up = U + p16 * 16 + 4 * g;
        aU[0] = (_Float16)up[0];
        aU[1] = (_Float16)up[1];
        aU[2] = (_Float16)up[2];
        aU[3] = (_Float16)up[3];
    }
    // A2 = tiled PauliZ signs: Ztile[p16][e=4g+i], wire=p16&3 (exact in f16)
    half4 aS;
    {
        int w = p16 & 3;
        #pragma unroll
        for (int i = 0; i < 4; ++i) {
            int e = 4 * g + i;
            aS[i] = ((e >> (3 - w)) & 1) ? (_Float16)-1.f : (_Float16)1.f;
        }
    }

    int cnt = ipw + (wave < rem ? 1 : 0);
    if (cnt <= 0) return;
    const int mac0 = wave * ipw + (wave < rem ? wave : rem);
    const int nPairs = total >> 1;

    // pixels for this lane's patch pair of macro-iter j (clamped, branch-free)
    auto ldp = [&](int j, float4& t4, float4& b4) {
        int PR = (mac0 + j) * 64 + lane;
        if (PR >= nPairs) PR = nPairs - 1;
        int P   = PR * 2;
        int img = P / 196;                  // compiler magic-mul
        int pp  = P - img * 196;            // even, [0,194]
        int r   = (pp * 2341) >> 15;        // pp/14
        const float4* ptr = reinterpret_cast<const float4*>(x + img * 784 + 2 * pp + 28 * r);
        t4 = ptr[0];                        // top row: patches P,P+1
        b4 = ptr[7];                        // +28 floats
    };

    // factors for macro-iter jj -> LDS buffer jj&1 (2 x ds_write_b128)
    auto do_factors = [&](int jj, float4 T, float4 Bt) {
        unsigned int* buf = wbase + (jj & 1) * 512;
        uint2 awA, qwA, awB, qwB;
        factors(T.x, T.y, Bt.x, Bt.y, awA, qwA);   // patch 2*lane
        factors(T.z, T.w, Bt.z, Bt.w, awB, qwB);   // patch 2*lane+1
        *reinterpret_cast<uint4*>(buf + lane * 4)       = make_uint4(awA.x, awA.y, awB.x, awB.y);
        *reinterpret_cast<uint4*>(buf + 256 + lane * 4) = make_uint4(qwA.x, qwA.y, qwB.x, qwB.y);
    };

    float4 cT, cB, fT, fB;
    ldp(0, cT, cB);
    ldp(1, fT, fB);
    do_factors(0, cT, cB);       // prologue: buffer 0 ready

    for (int j = 0; j < cnt; ++j) {
        // rotate: pixels for j+1 were in flight; issue load for j+2
        cT = fT; cB = fB;
        ldp(j + 2, fT, fB);

        // factors for j+1 -> buffer (j+1)&1 (at j==cnt-1: clamped garbage, never read)
        do_factors(j + 1, cT, cB);

        // ---- phase 2 on buffer j&1 (written last iteration) ----
        const unsigned int* buf2 = wbase + (j & 1) * 512;
        const unsigned short* ap = reinterpret_cast<const unsigned short*>(buf2);
        const int pbase = (mac0 + j) * 128;

        #pragma unroll
        for (int th = 0; th < 2; ++th) {
            f32x4 mm[4];
            #pragma unroll
            for (int i = 0; i < 4; ++i) {
                const int t  = th * 4 + i;
                const int pt = t * 16 + p16;
                unsigned int av = ap[pt * 4 + g];                   // ds_read_u16, imm t*128
                unsigned int dup = (av << 16) | av;                 // v_lshl_or_b32
                uint2 qw = *reinterpret_cast<const uint2*>(buf2 + 256 + pt * 2);

                h2 ag  = __builtin_bit_cast(h2, dup);
                h2 q01 = __builtin_bit_cast(h2, qw.x);
                h2 q23 = __builtin_bit_cast(h2, qw.y);
                h2 blo = ag * q01;                                  // v_pk_mul_f16
                h2 bhi = ag * q23;
                half4 bST = __builtin_shufflevector(blo, bhi, 0, 1, 2, 3);

                const f32x4 zero4 = {0.f, 0.f, 0.f, 0.f};
                f32x4 y = __builtin_amdgcn_mfma_f32_16x16x16f16(aU, bST, zero4, 0, 0, 0);

                h2 y01 = __builtin_bit_cast(h2, pk(y[0], y[1]));
                h2 y23 = __builtin_bit_cast(h2, pk(y[2], y[3]));
                h2 p01 = y01 * y01;
                h2 p23 = y23 * y23;
                half4 bP = __builtin_shufflevector(p01, p23, 0, 1, 2, 3);

                mm[i] = __builtin_amdgcn_mfma_f32_16x16x16f16(aS, bP, zero4, 0, 0, 0);
            }
            // all 4 groups hold identical mm -> group g stores sub-batch th*4+g
            f32x4 sa  = (g & 1) ? mm[1] : mm[0];
            f32x4 sb  = (g & 1) ? mm[3] : mm[2];
            f32x4 sel = (g & 2) ? sb : sa;
            int Ps = pbase + th * 64 + lane;    // = pbase + (th*4+g)*16 + p16
            if (Ps < total)
                __builtin_nontemporal_store(sel, reinterpret_cast<f32x4*>(out + (size_t)Ps * 4));
        }
    }
}

extern "C" void kernel_launch(void* const* d_in, const int* in_sizes, int n_in,
                              void* d_out, int out_size, void* d_ws, size_t ws_size,
                              hipStream_t stream) {
    const float* x = (const float*)d_in[0];
    const float* U = (const float*)d_in[1];
    float* out = (float*)d_out;

    int B = in_sizes[0] / 784;
    int total = B * 196;                  // 6,422,528 patches
    int nPairs = total / 2;               // 3,211,264 aligned pairs
    int nmac = (nPairs + 63) / 64;        // 50,176 macro-iters (128 patches each)

    // 1792 blocks = 7 blocks/CU (16 KiB LDS each = 112 KiB), 7168 waves:
    // 50176 / 7168 = 7 exactly -> rem 0, perfectly balanced, no tail.
    int nblocks = 1792;
    int nwaves = nblocks * (256 / 64);
    int ipw = nmac / nwaves;
    int rem = nmac % nwaves;

    quanv<<<nblocks, 256, 0, stream>>>(x, U, out, total, ipw, rem);
}